// Round 10
// baseline (233.352 us; speedup 1.0000x reference)
//
#include <hip/hip_runtime.h>
#include <hip/hip_bf16.h>

#define EPSN 1e-12f
#define EPSL 1e-10f
#define KSPLIT 16
#define CHK 256

typedef __attribute__((ext_vector_type(8))) short short8;
typedef __attribute__((ext_vector_type(4))) float f32x4;

__device__ __forceinline__ unsigned f2bf(float f) {
  union { float f; unsigned u; } x; x.f = f;
  unsigned r = x.u + 0x7FFFu + ((x.u >> 16) & 1u);
  return r >> 16;
}

// Kernel 1: per-row prep (unchanged from R9, passing).
__global__ __launch_bounds__(256)
void prep_kernel(const float* __restrict__ emb, float* __restrict__ eC,
                 unsigned short* __restrict__ lpB, float* __restrict__ plp,
                 float* __restrict__ S, float* __restrict__ v, int N) {
  int w = threadIdx.x >> 6, l = threadIdx.x & 63;
  int row = blockIdx.x * 4 + w;
  if (row >= N) return;
  const float* x = emb + (size_t)row * 128;
  float2 xv = *(const float2*)(x + 2 * l);
  float s4 = xv.x*xv.x*xv.x*xv.x + xv.y*xv.y*xv.y*xv.y;
  #pragma unroll
  for (int m = 1; m < 64; m <<= 1) s4 += __shfl_xor(s4, m);
  float denom = fmaxf(sqrtf(sqrtf(s4)), EPSN);
  float e0 = xv.x / denom, e1 = xv.y / denom;
  float lp0 = logf(e0 + EPSL), lp1 = logf(e1 + EPSL);
  int Rg = row >> 4, lhig = (row >> 2) & 3, rg = row & 3;
  int d0 = 2 * l, d1 = 2 * l + 1;
  eC[(((size_t)Rg * 8 + (d0 >> 4)) * 64 + (d0 & 15) + 16 * lhig) * 4 + rg] = e0;
  eC[(((size_t)Rg * 8 + (d1 >> 4)) * 64 + (d1 & 15) + 16 * lhig) * 4 + rg] = e1;
  int ksr = row >> 5, lhir = (row >> 3) & 3, jr = row & 7;
  lpB[((size_t)(ksr*8 + (d0>>4))*64 + (d0&15) + 16*lhir)*8 + jr] = (unsigned short)f2bf(lp0);
  lpB[((size_t)(ksr*8 + (d1>>4))*64 + (d1&15) + 16*lhir)*8 + jr] = (unsigned short)f2bf(lp1);
  float pl = e0 * lp0 + e1 * lp1;
  #pragma unroll
  for (int m = 1; m < 64; m <<= 1) pl += __shfl_xor(pl, m);
  if (l == 0) { plp[row] = pl; S[row] = 0.f; v[row] = 0.f; }
}

// Kernel 2: fused GEMM M = adj @ log_p. 64-row x 768-k tile, 3 chunks of 256k.
// A: 1KB-contiguous-per-instruction nontemporal loads -> reg -> cvt(bf16) +
// fused rowsum -> XOR-swizzled LDS dbuf. B: wave-private col-frag registers,
// loaded (cacheable, L2-hot) at iter start BEFORE the A-prefetch (vmcnt-order
// safe). One __syncthreads per chunk. All reg arrays statically indexed.
__global__ __launch_bounds__(256)
void gemm_kernel(const float* __restrict__ adj, const float* __restrict__ eC,
                 const unsigned short* __restrict__ lpB,
                 float* __restrict__ S, float* __restrict__ v, int N) {
  __shared__ unsigned short ash[2][64 * CHK];  // 2 x 32KB
  int w = threadIdx.x >> 6, l = threadIdx.x & 63;
  int l16 = l & 15, lhi = l >> 4;
  int row0 = blockIdx.x * 64;
  int k0 = blockIdx.y * (12288 / KSPLIT);  // kr = 768

  f32x4 acc[4][2];
  #pragma unroll
  for (int i = 0; i < 4; ++i) {
    acc[i][0] = (f32x4){0.f, 0.f, 0.f, 0.f};
    acc[i][1] = (f32x4){0.f, 0.f, 0.f, 0.f};
  }
  float sAcc[16];
  #pragma unroll
  for (int j = 0; j < 16; ++j) sAcc[j] = 0.f;

  // A staging: wave w owns rows 16w..16w+15; lane l covers floats 4l..4l+3.
  const float* aBase = adj + (size_t)(row0 + 16 * w) * N + k0 + 4 * l;
  f32x4 ar[16];
  short8 bb[2][8];

#define LOADA(t)                                                        \
  {                                                                     \
    _Pragma("unroll")                                                   \
    for (int j_ = 0; j_ < 16; ++j_)                                     \
      ar[j_] = __builtin_nontemporal_load(                              \
          (const f32x4*)(aBase + (size_t)j_ * N + (t) * CHK));          \
  }

#define LOADB(t)                                                        \
  {                                                                     \
    size_t fb_ = (size_t)((k0 + (t) * CHK) >> 5) * 8;                   \
    _Pragma("unroll")                                                   \
    for (int kg_ = 0; kg_ < 8; ++kg_) {                                 \
      bb[0][kg_] = ((const short8*)lpB)[(fb_ + kg_*8 + 2*w    ) * 64 + l]; \
      bb[1][kg_] = ((const short8*)lpB)[(fb_ + kg_*8 + 2*w + 1) * 64 + l]; \
    }                                                                   \
  }

#define STAGE(bi)                                                       \
  {                                                                     \
    char* q_ = (char*)ash[bi];                                          \
    _Pragma("unroll")                                                   \
    for (int j_ = 0; j_ < 16; ++j_) {                                   \
      f32x4 x_ = ar[j_];                                                \
      sAcc[j_] += (x_[0] + x_[1]) + (x_[2] + x_[3]);                    \
      unsigned p0_ = f2bf(x_[0]) | (f2bf(x_[1]) << 16);                 \
      unsigned p1_ = f2bf(x_[2]) | (f2bf(x_[3]) << 16);                 \
      int rl_ = 16 * w + j_;                                            \
      *(uint2*)(q_ + rl_ * 512 + ((8 * l) ^ ((rl_ & 7) << 4))) =        \
          make_uint2(p0_, p1_);                                         \
    }                                                                   \
  }

#define COMP(bi)                                                        \
  {                                                                     \
    const char* base_ = (const char*)ash[bi];                           \
    int xr_ = (l16 & 7) << 4;                                           \
    _Pragma("unroll")                                                   \
    for (int kg_ = 0; kg_ < 8; ++kg_) {                                 \
      int off_ = (kg_ * 64 + lhi * 16) ^ xr_;                           \
      short8 a0_ = *(const short8*)(base_ + (l16     ) * 512 + off_);   \
      short8 a1_ = *(const short8*)(base_ + (l16 + 16) * 512 + off_);   \
      short8 a2_ = *(const short8*)(base_ + (l16 + 32) * 512 + off_);   \
      short8 a3_ = *(const short8*)(base_ + (l16 + 48) * 512 + off_);   \
      acc[0][0] = __builtin_amdgcn_mfma_f32_16x16x32_bf16(a0_, bb[0][kg_], acc[0][0], 0, 0, 0); \
      acc[0][1] = __builtin_amdgcn_mfma_f32_16x16x32_bf16(a0_, bb[1][kg_], acc[0][1], 0, 0, 0); \
      acc[1][0] = __builtin_amdgcn_mfma_f32_16x16x32_bf16(a1_, bb[0][kg_], acc[1][0], 0, 0, 0); \
      acc[1][1] = __builtin_amdgcn_mfma_f32_16x16x32_bf16(a1_, bb[1][kg_], acc[1][1], 0, 0, 0); \
      acc[2][0] = __builtin_amdgcn_mfma_f32_16x16x32_bf16(a2_, bb[0][kg_], acc[2][0], 0, 0, 0); \
      acc[2][1] = __builtin_amdgcn_mfma_f32_16x16x32_bf16(a2_, bb[1][kg_], acc[2][1], 0, 0, 0); \
      acc[3][0] = __builtin_amdgcn_mfma_f32_16x16x32_bf16(a3_, bb[0][kg_], acc[3][0], 0, 0, 0); \
      acc[3][1] = __builtin_amdgcn_mfma_f32_16x16x32_bf16(a3_, bb[1][kg_], acc[3][1], 0, 0, 0); \
    }                                                                   \
  }

  // Schedule (chunks 0,1,2; buf = chunk&1):
  LOADA(0); STAGE(0);
  __syncthreads();
  LOADB(0); LOADA(1); COMP(0); STAGE(1);
  __syncthreads();
  LOADB(1); LOADA(2); COMP(1); STAGE(0);
  __syncthreads();
  LOADB(2); COMP(0);

  // adj rowsum: sAcc[j] -> row row0+16w+j; full-wave reduce, 1 atomic/row.
  #pragma unroll
  for (int j = 0; j < 16; ++j) {
    float s = sAcc[j];
    #pragma unroll
    for (int m = 1; m < 64; m <<= 1) s += __shfl_xor(s, m);
    if (l == 0) atomicAdd(&S[row0 + 16 * w + j], s);
  }

  // v[i] += sum over this wave's 32 cols of e[i,d]*C[i,d] via fragment eC.
  // C layout: lane(l16,lhi) reg r -> row = rt*16 + lhi*4 + r, col = ct*16 + l16.
  #pragma unroll
  for (int rt = 0; rt < 4; ++rt) {
    int R = (row0 >> 4) + rt;
    float p0 = 0.f, p1 = 0.f, p2 = 0.f, p3 = 0.f;
    #pragma unroll
    for (int c = 0; c < 2; ++c) {
      int ct = 2 * w + c;
      f32x4 ef = *(const f32x4*)(eC + (((size_t)R * 8 + ct) * 64 + l) * 4);
      p0 += ef[0] * acc[rt][c][0];
      p1 += ef[1] * acc[rt][c][1];
      p2 += ef[2] * acc[rt][c][2];
      p3 += ef[3] * acc[rt][c][3];
    }
    #pragma unroll
    for (int m = 1; m < 16; m <<= 1) {
      p0 += __shfl_xor(p0, m);
      p1 += __shfl_xor(p1, m);
      p2 += __shfl_xor(p2, m);
      p3 += __shfl_xor(p3, m);
    }
    if (l16 == 0) {
      int rb = row0 + rt * 16 + lhi * 4;
      atomicAdd(&v[rb + 0], p0);
      atomicAdd(&v[rb + 1], p1);
      atomicAdd(&v[rb + 2], p2);
      atomicAdd(&v[rb + 3], p3);
    }
  }
}

// Kernel 3: out = lambda * sum_i [ plp[i]*(S_i/max(S_i,eps)) - v[i]/max(S_i,eps) ]
__global__ __launch_bounds__(1024)
void final_kernel(const float* __restrict__ plp, const float* __restrict__ S,
                  const float* __restrict__ v, const float* __restrict__ lam,
                  float* __restrict__ out, int N) {
  __shared__ float red[16];
  float acc = 0.f;
  for (int i = threadIdx.x; i < N; i += 1024) {
    float s = S[i], d = fmaxf(s, EPSN);
    acc += plp[i] * (s / d) - v[i] / d;
  }
  #pragma unroll
  for (int m = 1; m < 64; m <<= 1) acc += __shfl_xor(acc, m);
  int w = threadIdx.x >> 6, l = threadIdx.x & 63;
  if (l == 0) red[w] = acc;
  __syncthreads();
  if (threadIdx.x == 0) {
    float t = 0.f;
    #pragma unroll
    for (int i = 0; i < 16; ++i) t += red[i];
    out[0] = lam[0] * t;
  }
}

extern "C" void kernel_launch(void* const* d_in, const int* in_sizes, int n_in,
                              void* d_out, int out_size, void* d_ws, size_t ws_size,
                              hipStream_t stream) {
  const float* emb = (const float*)d_in[0];
  const float* adj = (const float*)d_in[1];
  const float* lam = (const float*)d_in[2];
  int N = in_sizes[0] / 128;  // D = 128 per reference (N = 12288)

  char* ws = (char*)d_ws;
  float* eC           = (float*)ws;                                 // N*128 f32 (C-frag layout)
  unsigned short* lpB = (unsigned short*)(ws + (size_t)N * 512);    // N*128 bf16 (B-frag layout)
  float* plp          = (float*)(ws + (size_t)N * 768);             // N f32
  float* S            = plp + N;                                    // N f32
  float* v            = S + N;                                      // N f32

  prep_kernel<<<(N + 3) / 4, 256, 0, stream>>>(emb, eC, lpB, plp, S, v, N);
  dim3 grid(N / 64, KSPLIT);
  gemm_kernel<<<grid, 256, 0, stream>>>(adj, eC, lpB, S, v, N);
  final_kernel<<<1, 1024, 0, stream>>>(plp, S, v, lam, (float*)d_out, N);
}

// Round 11
// 200.213 us; speedup vs baseline: 1.1655x; 1.1655x over previous
//
#include <hip/hip_runtime.h>
#include <hip/hip_bf16.h>

#define EPSN 1e-12f
#define EPSL 1e-10f
#define KSPLIT 64
#define KS 64

typedef __attribute__((ext_vector_type(8))) short short8;
typedef __attribute__((ext_vector_type(4))) float f32x4;

__device__ __forceinline__ unsigned f2bf(float f) {
  union { float f; unsigned u; } x; x.f = f;
  unsigned r = x.u + 0x7FFFu + ((x.u >> 16) & 1u);
  return r >> 16;
}

// Kernel 1: per-row prep (unchanged champion).
__global__ __launch_bounds__(256)
void prep_kernel(const float* __restrict__ emb, float* __restrict__ eC,
                 unsigned short* __restrict__ lpB, float* __restrict__ plp,
                 float* __restrict__ S, float* __restrict__ v, int N) {
  int w = threadIdx.x >> 6, l = threadIdx.x & 63;
  int row = blockIdx.x * 4 + w;
  if (row >= N) return;
  const float* x = emb + (size_t)row * 128;
  float2 xv = *(const float2*)(x + 2 * l);
  float s4 = xv.x*xv.x*xv.x*xv.x + xv.y*xv.y*xv.y*xv.y;
  #pragma unroll
  for (int m = 1; m < 64; m <<= 1) s4 += __shfl_xor(s4, m);
  float denom = fmaxf(sqrtf(sqrtf(s4)), EPSN);
  float e0 = xv.x / denom, e1 = xv.y / denom;
  float lp0 = logf(e0 + EPSL), lp1 = logf(e1 + EPSL);
  int Rg = row >> 4, lhig = (row >> 2) & 3, rg = row & 3;
  int d0 = 2 * l, d1 = 2 * l + 1;
  eC[(((size_t)Rg * 8 + (d0 >> 4)) * 64 + (d0 & 15) + 16 * lhig) * 4 + rg] = e0;
  eC[(((size_t)Rg * 8 + (d1 >> 4)) * 64 + (d1 & 15) + 16 * lhig) * 4 + rg] = e1;
  int ksr = row >> 5, lhir = (row >> 3) & 3, jr = row & 7;
  lpB[((size_t)(ksr*8 + (d0>>4))*64 + (d0&15) + 16*lhir)*8 + jr] = (unsigned short)f2bf(lp0);
  lpB[((size_t)(ksr*8 + (d1>>4))*64 + (d1&15) + 16*lhir)*8 + jr] = (unsigned short)f2bf(lp1);
  float pl = e0 * lp0 + e1 * lp1;
  #pragma unroll
  for (int m = 1; m < 64; m <<= 1) pl += __shfl_xor(pl, m);
  if (l == 0) { plp[row] = pl; S[row] = 0.f; v[row] = 0.f; }
}

// Kernel 2: R9 champion structure with FULL-K A prefetch: all 24 A-loads
// (3 K-steps x 8) issued in the prologue (nontemporal), B staged once to LDS
// (B loads issued FIRST -> in-order vmcnt retirement means the LDS writes
// never drain A). Barrier-free K-loop body: 3 fully-unrolled STEPs.
__global__ __launch_bounds__(256, 2)
void gemm_kernel(const float* __restrict__ adj, const float* __restrict__ eC,
                 const unsigned short* __restrict__ lpB,
                 float* __restrict__ S, float* __restrict__ v, int N) {
  __shared__ unsigned short bsh[KS * 3 * 128];  // 192k x 128d bf16 = 48KB
  int w = threadIdx.x >> 6, l = threadIdx.x & 63;
  int l16 = l & 15, lhi = l >> 4;
  int wrow0 = blockIdx.x * 128 + w * 32;
  int k0 = blockIdx.y * (N / KSPLIT);   // kr = 192

  // A: lane (l16,lhi) reads rows wrow0+l16 / +16, k = k0+s*64+ks*32+lhi*8
  const float* rp0 = adj + (size_t)(wrow0 + l16) * N + k0 + lhi * 8;
  const float* rp1 = rp0 + (size_t)16 * N;

  f32x4 a0[2][2][2], a1[2][2][2], a2[2][2][2];
  short8 breg[12];

#define LOADA(buf, s)                                                   \
  {                                                                     \
    _Pragma("unroll")                                                   \
    for (int rt_ = 0; rt_ < 2; ++rt_) {                                 \
      const float* bp_ = (rt_ ? rp1 : rp0) + (s) * KS;                  \
      _Pragma("unroll")                                                 \
      for (int ks_ = 0; ks_ < 2; ++ks_) {                               \
        buf[rt_][ks_][0] = __builtin_nontemporal_load((const f32x4*)(bp_ + ks_ * 32));     \
        buf[rt_][ks_][1] = __builtin_nontemporal_load((const f32x4*)(bp_ + ks_ * 32 + 4)); \
      }                                                                 \
    }                                                                   \
  }

  // ---- prologue: issue B (12 cacheable loads) FIRST, then all 24 A loads ----
  {
    const short8* gB = (const short8*)(lpB + (size_t)k0 * 128);
    #pragma unroll
    for (int i = 0; i < 12; ++i) breg[i] = gB[(w * 12 + i) * 64 + l];
  }
  LOADA(a0, 0);
  LOADA(a1, 1);
  LOADA(a2, 2);
  {
    short8* sB = (short8*)bsh;
    #pragma unroll
    for (int i = 0; i < 12; ++i) sB[(w * 12 + i) * 64 + l] = breg[i];
  }

  f32x4 acc[2][8];
  #pragma unroll
  for (int i = 0; i < 2; ++i)
    #pragma unroll
    for (int j = 0; j < 8; ++j) acc[i][j] = (f32x4){0.f, 0.f, 0.f, 0.f};
  float sAcc[2] = {0.f, 0.f};

#define STEP(buf, s)                                                    \
  {                                                                     \
    _Pragma("unroll")                                                   \
    for (int ks_ = 0; ks_ < 2; ++ks_) {                                 \
      short8 bb_[8];                                                    \
      _Pragma("unroll")                                                 \
      for (int ct_ = 0; ct_ < 8; ++ct_)                                 \
        bb_[ct_] = *((const short8*)bsh + ((size_t)(((s)*2 + ks_)*8 + ct_))*64 + l); \
      short8 af_[2];                                                    \
      _Pragma("unroll")                                                 \
      for (int rt_ = 0; rt_ < 2; ++rt_) {                               \
        f32x4 x0_ = buf[rt_][ks_][0], x1_ = buf[rt_][ks_][1];           \
        sAcc[rt_] += ((x0_[0] + x0_[1]) + (x0_[2] + x0_[3])) +          \
                     ((x1_[0] + x1_[1]) + (x1_[2] + x1_[3]));           \
        short8 t_;                                                      \
        t_[0] = (short)f2bf(x0_[0]); t_[1] = (short)f2bf(x0_[1]);       \
        t_[2] = (short)f2bf(x0_[2]); t_[3] = (short)f2bf(x0_[3]);       \
        t_[4] = (short)f2bf(x1_[0]); t_[5] = (short)f2bf(x1_[1]);       \
        t_[6] = (short)f2bf(x1_[2]); t_[7] = (short)f2bf(x1_[3]);       \
        af_[rt_] = t_;                                                  \
      }                                                                 \
      _Pragma("unroll")                                                 \
      for (int ct_ = 0; ct_ < 8; ++ct_) {                               \
        acc[0][ct_] = __builtin_amdgcn_mfma_f32_16x16x32_bf16(af_[0], bb_[ct_], acc[0][ct_], 0, 0, 0); \
        acc[1][ct_] = __builtin_amdgcn_mfma_f32_16x16x32_bf16(af_[1], bb_[ct_], acc[1][ct_], 0, 0, 0); \
      }                                                                 \
    }                                                                   \
  }

  __syncthreads();   // B staged; all A loads already in flight

  STEP(a0, 0);
  STEP(a1, 1);
  STEP(a2, 2);

  // adj rowsum partials: lane (l16,lhi) holds row (wrow0+rt*16+l16)'s lhi-slice.
  #pragma unroll
  for (int rt = 0; rt < 2; ++rt) {
    float s = sAcc[rt];
    s += __shfl_xor(s, 16);
    s += __shfl_xor(s, 32);
    if (l < 16) atomicAdd(&S[wrow0 + rt * 16 + l], s);
  }

  // v[i] += sum_d e[i,d]*C_part[i,d] via fragment-layout eC (coalesced frags).
  #pragma unroll
  for (int rt = 0; rt < 2; ++rt) {
    int R = (wrow0 >> 4) + rt;
    float p0 = 0.f, p1 = 0.f, p2 = 0.f, p3 = 0.f;
    #pragma unroll
    for (int ct = 0; ct < 8; ++ct) {
      f32x4 ef = *(const f32x4*)(eC + (((size_t)R * 8 + ct) * 64 + l) * 4);
      p0 += ef[0] * acc[rt][ct][0];
      p1 += ef[1] * acc[rt][ct][1];
      p2 += ef[2] * acc[rt][ct][2];
      p3 += ef[3] * acc[rt][ct][3];
    }
    #pragma unroll
    for (int m = 1; m < 16; m <<= 1) {
      p0 += __shfl_xor(p0, m);
      p1 += __shfl_xor(p1, m);
      p2 += __shfl_xor(p2, m);
      p3 += __shfl_xor(p3, m);
    }
    if (l16 == 0) {
      int rowb = wrow0 + rt * 16 + lhi * 4;
      atomicAdd(&v[rowb + 0], p0);
      atomicAdd(&v[rowb + 1], p1);
      atomicAdd(&v[rowb + 2], p2);
      atomicAdd(&v[rowb + 3], p3);
    }
  }
}

// Kernel 3: out = lambda * sum_i [ plp[i]*(S_i/max(S_i,eps)) - v[i]/max(S_i,eps) ]
__global__ __launch_bounds__(1024)
void final_kernel(const float* __restrict__ plp, const float* __restrict__ S,
                  const float* __restrict__ v, const float* __restrict__ lam,
                  float* __restrict__ out, int N) {
  __shared__ float red[16];
  float acc = 0.f;
  for (int i = threadIdx.x; i < N; i += 1024) {
    float s = S[i], d = fmaxf(s, EPSN);
    acc += plp[i] * (s / d) - v[i] / d;
  }
  #pragma unroll
  for (int m = 1; m < 64; m <<= 1) acc += __shfl_xor(acc, m);
  int w = threadIdx.x >> 6, l = threadIdx.x & 63;
  if (l == 0) red[w] = acc;
  __syncthreads();
  if (threadIdx.x == 0) {
    float t = 0.f;
    #pragma unroll
    for (int i = 0; i < 16; ++i) t += red[i];
    out[0] = lam[0] * t;
  }
}

extern "C" void kernel_launch(void* const* d_in, const int* in_sizes, int n_in,
                              void* d_out, int out_size, void* d_ws, size_t ws_size,
                              hipStream_t stream) {
  const float* emb = (const float*)d_in[0];
  const float* adj = (const float*)d_in[1];
  const float* lam = (const float*)d_in[2];
  int N = in_sizes[0] / 128;  // D = 128 per reference (N = 12288)

  char* ws = (char*)d_ws;
  float* eC           = (float*)ws;                                 // N*128 f32 (C-frag layout)
  unsigned short* lpB = (unsigned short*)(ws + (size_t)N * 512);    // N*128 bf16 (B-frag layout)
  float* plp          = (float*)(ws + (size_t)N * 768);             // N f32
  float* S            = plp + N;                                    // N f32
  float* v            = S + N;                                      // N f32

  prep_kernel<<<(N + 3) / 4, 256, 0, stream>>>(emb, eC, lpB, plp, S, v, N);
  dim3 grid(N / 128, KSPLIT);
  gemm_kernel<<<grid, 256, 0, stream>>>(adj, eC, lpB, S, v, N);
  final_kernel<<<1, 1024, 0, stream>>>(plp, S, v, lam, (float*)d_out, N);
}